// Round 4
// baseline (763.679 us; speedup 1.0000x reference)
//
#include <hip/hip_runtime.h>

#define N_NODES 50000
#define N_EDGES 800000

typedef unsigned int u32;
typedef unsigned short u16;
typedef __attribute__((ext_vector_type(2))) float float2v;

__device__ __forceinline__ float bf_lo(u32 v){ return __uint_as_float(v << 16); }
__device__ __forceinline__ float bf_hi(u32 v){ return __uint_as_float(v & 0xffff0000u); }
__device__ __forceinline__ u16 f2bf(float f){
    u32 u = __float_as_uint(f);
    u += 0x7fffu + ((u >> 16) & 1u);     // round-to-nearest-even
    return (u16)(u >> 16);
}

#if __has_builtin(__builtin_amdgcn_cvt_pk_f32_fp8) && __has_builtin(__builtin_amdgcn_cvt_pk_fp8_f32)
#define HW_FP8 1
#else
#define HW_FP8 0
#endif

__device__ __forceinline__ u32 enc1_e4m3(float f){
    u32 u = __float_as_uint(f);
    u32 s = (u >> 24) & 0x80u;
    u32 a = u & 0x7fffffffu;
    if (a >= 0x43e00000u) return s | 0x7eu;          // >= 448 -> sat
    if (a < 0x3c800000u){                            // < 2^-6 -> denormal (m * 2^-9)
        float af = __uint_as_float(a) * 512.f;
        u32 m = (u32)(af + 0.5f);
        return s | m;                                // m==8 correctly becomes min normal
    }
    int e = (int)(a >> 23) - 127;
    u32 mant = (a >> 20) & 7u;
    u32 rnd = (a >> 19) & 1u;
    u32 sticky = (a & 0x7ffffu) ? 1u : 0u;
    u32 code = ((u32)(e + 7) << 3) | mant;
    code += (rnd & (sticky | (mant & 1u)));
    if (code > 0x7eu) code = 0x7eu;
    return s | code;
}

__device__ __forceinline__ float2v dec2_e4m3(u32 v16){
#if HW_FP8
    return __builtin_amdgcn_cvt_pk_f32_fp8(v16, false);
#else
    float2v r;
    #pragma unroll
    for (int t = 0; t < 2; t++){
        u32 b = (v16 >> (8 * t)) & 0xffu;
        u32 e = (b >> 3) & 15u, m = b & 7u;
        float v = e ? __uint_as_float(((e + 120u) << 23) | (m << 20)) : (float)m * 0.001953125f;
        r[t] = (b & 0x80u) ? -v : v;
    }
    return r;
#endif
}
__device__ __forceinline__ u32 encpk_lo(float a, float b, u32 old){
#if HW_FP8
    return (u32)__builtin_amdgcn_cvt_pk_fp8_f32(a, b, (int)old, false);
#else
    return (old & 0xffff0000u) | enc1_e4m3(a) | (enc1_e4m3(b) << 8);
#endif
}
__device__ __forceinline__ u32 encpk_hi(float a, float b, u32 old){
#if HW_FP8
    return (u32)__builtin_amdgcn_cvt_pk_fp8_f32(a, b, (int)old, true);
#else
    return (old & 0x0000ffffu) | (enc1_e4m3(a) << 16) | (enc1_e4m3(b) << 24);
#endif
}

// ---------------------------------------------------------------- zero counts
__global__ void zero_cnt_kernel(u32* __restrict__ cnt){
    int i = blockIdx.x * 1024 + threadIdx.x;
    if (i < 2 * N_NODES) cnt[i] = 0u;
}

// ------------------------------------------------------- pack weights to bf16
// Wcat1[k][256] = [w_e1 top | w_e1 bottom]   (score path A|B)
// Wmsg [k][256] = [w_s2d | w_d2s]            (message post-GEMM)
__global__ void prep_kernel(const float* __restrict__ w_s2d, const float* __restrict__ w_d2s,
                            const float* __restrict__ w_e1, const float* __restrict__ w_g1,
                            const float* __restrict__ b_e1,
                            u16* __restrict__ Wcat1, u16* __restrict__ Wmsg,
                            u16* __restrict__ Wg1b, float* __restrict__ bias1){
    int idx = blockIdx.x * 256 + threadIdx.x;
    if (idx < 32768){
        int k = idx >> 8, o = idx & 255;
        float v = (o < 128) ? w_e1[k * 128 + o] : w_e1[(128 + k) * 128 + (o - 128)];
        Wcat1[idx] = f2bf(v);
    } else if (idx < 65536){
        int j = idx - 32768, k = j >> 8, o = j & 255;
        float v = (o < 128) ? w_s2d[k * 128 + o] : w_d2s[k * 128 + (o - 128)];
        Wmsg[j] = f2bf(v);
    } else if (idx < 98304){
        int j = idx - 65536;
        Wg1b[j] = f2bf(w_g1[j]);
    } else if (idx < 98560){
        int o = idx - 98304;
        bias1[o] = (o < 128) ? b_e1[o] : 0.f;
    }
}

// ------------------------------------------------------------- x -> bf16 copy
__global__ void xcast_kernel(const float* __restrict__ x, u32* __restrict__ xb){
    int i = blockIdx.x * 256 + threadIdx.x;      // one u32 (2 elems) per thread
    if (i < N_NODES * 64){
        float2 v = ((const float2*)x)[i];
        xb[i] = (u32)f2bf(v.x) | ((u32)f2bf(v.y) << 16);
    }
}

// --------------------------------------- score projections T1 = [A|B] in fp8
// T1 row = 256 bytes: A = bytes 0..127 (e4m3), B = bytes 128..255
__global__ __launch_bounds__(256) void proj_kernel(const float* __restrict__ x,
        const u16* __restrict__ Wcat, const float* __restrict__ bias,
        u32* __restrict__ T1){
    __shared__ float xs[32 * 132];
    const int tid = threadIdx.x;
    const int nb = blockIdx.x * 32;
    #pragma unroll
    for (int i = 0; i < 16; i++){
        int li = tid + i * 256;
        int nn = li >> 7, k = li & 127;
        int g = nb + nn;
        xs[nn * 132 + k] = (g < N_NODES) ? x[g * 128 + k] : 0.f;
    }
    __syncthreads();
    const int og = tid & 15, ng = tid >> 4;
    const int o0 = og * 16, n0 = ng * 2;
    float acc[2][16];
    #pragma unroll
    for (int j = 0; j < 2; j++)
        #pragma unroll
        for (int i = 0; i < 16; i++) acc[j][i] = 0.f;

    for (int k = 0; k < 128; k++){
        const uint4 wa = *(const uint4*)(Wcat + k * 256 + o0);
        const uint4 wb = *(const uint4*)(Wcat + k * 256 + o0 + 8);
        u32 w32[8] = {wa.x, wa.y, wa.z, wa.w, wb.x, wb.y, wb.z, wb.w};
        float wf[16];
        #pragma unroll
        for (int m = 0; m < 8; m++){ wf[2*m] = bf_lo(w32[m]); wf[2*m+1] = bf_hi(w32[m]); }
        float xv0 = xs[n0 * 132 + k];
        float xv1 = xs[(n0 + 1) * 132 + k];
        #pragma unroll
        for (int i = 0; i < 16; i++){ acc[0][i] += xv0 * wf[i]; acc[1][i] += xv1 * wf[i]; }
    }
    #pragma unroll
    for (int j = 0; j < 2; j++){
        int g = nb + n0 + j;
        if (g >= N_NODES) continue;
        u32 w32o[4];
        #pragma unroll
        for (int m = 0; m < 4; m++){
            float f0 = acc[j][4*m]   + bias[o0 + 4*m];
            float f1 = acc[j][4*m+1] + bias[o0 + 4*m+1];
            float f2 = acc[j][4*m+2] + bias[o0 + 4*m+2];
            float f3 = acc[j][4*m+3] + bias[o0 + 4*m+3];
            u32 w = encpk_lo(f0, f1, 0u);
            w32o[m] = encpk_hi(f2, f3, w);
        }
        *(uint4*)(T1 + g * 64 + og * 4) = make_uint4(w32o[0], w32o[1], w32o[2], w32o[3]);
    }
}

// ------------------------------------------- edge scores + degree histograms
__global__ __launch_bounds__(256) void edge_score_kernel(const u16* __restrict__ T1, const int* __restrict__ eidx,
        const float* __restrict__ w_e2, const float* __restrict__ b_e2,
        u16* __restrict__ score, u32* __restrict__ cnt_dst, u32* __restrict__ cnt_src){
    const int wave = threadIdx.x >> 6, lane = threadIdx.x & 63;
    const int e = blockIdx.x * 4 + wave;
    if (e >= N_EDGES) return;
    const int src = eidx[e];
    const int dst = eidx[N_EDGES + e];
    const u32 a16 = T1[src * 128 + lane];          // elems 2l,2l+1 of A
    const u32 b16 = T1[dst * 128 + 64 + lane];     // elems 2l,2l+1 of B
    float2v fa = dec2_e4m3(a16);
    float2v fb = dec2_e4m3(b16);
    const float2 w = ((const float2*)w_e2)[lane];
    float h0 = fmaxf(fa[0] + fb[0], 0.f);
    float h1 = fmaxf(fa[1] + fb[1], 0.f);
    float p = h0 * w.x + h1 * w.y;
    #pragma unroll
    for (int m = 32; m >= 1; m >>= 1) p += __shfl_xor(p, m, 64);
    if (lane == 0){
        float sc = 1.f / (1.f + __expf(-(p + b_e2[0])));
        score[e] = f2bf(sc);
        atomicAdd(cnt_dst + dst, 1u);
        atomicAdd(cnt_src + src, 1u);
    }
}

// ------------------------------------------------------- exclusive scan (x2)
__global__ __launch_bounds__(1024) void scan_kernel(const u32* __restrict__ cnt,
        u32* __restrict__ start_dst, u32* __restrict__ next_dst,
        u32* __restrict__ start_src, u32* __restrict__ next_src){
    __shared__ u32 sa[1024], sb[1024];
    const int t = threadIdx.x;
    const u32* c = cnt + (blockIdx.x ? N_NODES : 0);
    u32* st = blockIdx.x ? start_src : start_dst;
    u32* nx = blockIdx.x ? next_src  : next_dst;
    const int CH = 49;                       // 1024*49 = 50176 >= N
    const int base = t * CH;
    u32 s = 0;
    for (int j = 0; j < CH; j++){ int i = base + j; if (i < N_NODES) s += c[i]; }
    sa[t] = s; __syncthreads();
    u32* a = sa; u32* b = sb;
    for (int off = 1; off < 1024; off <<= 1){
        u32 v = a[t];
        if (t >= off) v += a[t - off];
        b[t] = v;
        __syncthreads();
        u32* tmp = a; a = b; b = tmp;
    }
    u32 run = (t == 0) ? 0u : a[t - 1];
    for (int j = 0; j < CH; j++){
        int i = base + j;
        if (i < N_NODES){ st[i] = run; nx[i] = run; run += c[i]; }
    }
}

// ------------------------------------------------- scatter edge payloads CSR
// payload u32: [score bf16 in high 16 | neighbor id in low 16]  (N < 65536)
__global__ __launch_bounds__(256) void scatter_kernel(const int* __restrict__ eidx, const u16* __restrict__ score,
        u32* __restrict__ next_dst, u32* __restrict__ next_src,
        u32* __restrict__ in_pay, u32* __restrict__ out_pay){
    int e = blockIdx.x * 256 + threadIdx.x;
    if (e >= N_EDGES) return;
    int src = eidx[e], dst = eidx[N_EDGES + e];
    u32 sc = (u32)score[e] << 16;
    u32 p1 = atomicAdd(next_dst + dst, 1u);
    in_pay[p1] = sc | (u32)src;
    u32 p2 = atomicAdd(next_src + src, 1u);
    out_pay[p2] = sc | (u32)dst;
}

// --------------------------------- gather weighted raw-x sums (both dirs)
// Y row (d_out as u32): words 0..63 = y_in (bf16 pair), 64..127 = y_out
__global__ __launch_bounds__(256) void gather_kernel(const u32* __restrict__ xb,
        const u32* __restrict__ in_pay, const u32* __restrict__ out_pay,
        const u32* __restrict__ cnt_dst, const u32* __restrict__ start_dst,
        const u32* __restrict__ cnt_src, const u32* __restrict__ start_src,
        u32* __restrict__ Y, float* __restrict__ ssin, float* __restrict__ ssout){
    const int wave = threadIdx.x >> 6, lane = threadIdx.x & 63;
    const int node = blockIdx.x * 4 + wave;
    if (node >= N_NODES) return;
    {
        u32 deg = cnt_dst[node], st = start_dst[node];
        float a0 = 0.f, a1 = 0.f, ss = 0.f;
        u32 j = 0;
        for (; j + 4 <= deg; j += 4){
            u32 p0 = in_pay[st+j], p1 = in_pay[st+j+1], p2 = in_pay[st+j+2], p3 = in_pay[st+j+3];
            u32 v0 = xb[(p0 & 0xffffu)*64 + lane], v1 = xb[(p1 & 0xffffu)*64 + lane];
            u32 v2 = xb[(p2 & 0xffffu)*64 + lane], v3 = xb[(p3 & 0xffffu)*64 + lane];
            float s0 = __uint_as_float(p0 & 0xffff0000u), s1 = __uint_as_float(p1 & 0xffff0000u);
            float s2 = __uint_as_float(p2 & 0xffff0000u), s3 = __uint_as_float(p3 & 0xffff0000u);
            a0 += s0*bf_lo(v0) + s1*bf_lo(v1) + s2*bf_lo(v2) + s3*bf_lo(v3);
            a1 += s0*bf_hi(v0) + s1*bf_hi(v1) + s2*bf_hi(v2) + s3*bf_hi(v3);
            ss += s0 + s1 + s2 + s3;
        }
        for (; j < deg; j++){
            u32 pl = in_pay[st + j];
            u32 v = xb[(pl & 0xffffu)*64 + lane];
            float sc = __uint_as_float(pl & 0xffff0000u);
            a0 += sc * bf_lo(v); a1 += sc * bf_hi(v); ss += sc;
        }
        Y[node * 128 + lane] = (u32)f2bf(a0) | ((u32)f2bf(a1) << 16);
        if (lane == 0) ssin[node] = ss;
    }
    {
        u32 deg = cnt_src[node], st = start_src[node];
        float a0 = 0.f, a1 = 0.f, ss = 0.f;
        u32 j = 0;
        for (; j + 4 <= deg; j += 4){
            u32 p0 = out_pay[st+j], p1 = out_pay[st+j+1], p2 = out_pay[st+j+2], p3 = out_pay[st+j+3];
            u32 v0 = xb[(p0 & 0xffffu)*64 + lane], v1 = xb[(p1 & 0xffffu)*64 + lane];
            u32 v2 = xb[(p2 & 0xffffu)*64 + lane], v3 = xb[(p3 & 0xffffu)*64 + lane];
            float s0 = __uint_as_float(p0 & 0xffff0000u), s1 = __uint_as_float(p1 & 0xffff0000u);
            float s2 = __uint_as_float(p2 & 0xffff0000u), s3 = __uint_as_float(p3 & 0xffff0000u);
            a0 += s0*bf_lo(v0) + s1*bf_lo(v1) + s2*bf_lo(v2) + s3*bf_lo(v3);
            a1 += s0*bf_hi(v0) + s1*bf_hi(v1) + s2*bf_hi(v2) + s3*bf_hi(v3);
            ss += s0 + s1 + s2 + s3;
        }
        for (; j < deg; j++){
            u32 pl = out_pay[st + j];
            u32 v = xb[(pl & 0xffffu)*64 + lane];
            float sc = __uint_as_float(pl & 0xffff0000u);
            a0 += sc * bf_lo(v); a1 += sc * bf_hi(v); ss += sc;
        }
        Y[node * 128 + 64 + lane] = (u32)f2bf(a0) | ((u32)f2bf(a1) << 16);
        if (lane == 0) ssout[node] = ss;
    }
}

// -------------------- finale: msg GEMMs + normalize + gate MLP + fuse + res
__global__ __launch_bounds__(256) void finale_kernel(const u32* __restrict__ Y,
        const float* __restrict__ x,
        const u16* __restrict__ Wmsg, const float* __restrict__ b_s2d, const float* __restrict__ b_d2s,
        const float* __restrict__ ssin, const float* __restrict__ ssout,
        const u32* __restrict__ cnt_dst, const u32* __restrict__ cnt_src,
        const u16* __restrict__ Wg1b, const float* __restrict__ b_g1,
        const float* __restrict__ w_g2, const float* __restrict__ b_g2,
        float* __restrict__ out){
    __shared__ u32 ysh[32][128];
    __shared__ float gin[32 * 256];
    __shared__ float part[32 * 33];
    __shared__ float gl[32];
    __shared__ float sA[32], sB[32], dA[32], dB[32];
    const int tid = threadIdx.x;
    const int nb = blockIdx.x * 32;
    #pragma unroll
    for (int i = 0; i < 16; i++){
        int li = tid + i * 256;
        int nn = li >> 7, w = li & 127;
        int g = nb + nn;
        ysh[nn][w] = (g < N_NODES) ? Y[g * 128 + w] : 0u;
    }
    if (tid < 32){
        int g = nb + tid;
        bool ok = g < N_NODES;
        sA[tid] = ok ? ssin[g]  : 0.f;
        sB[tid] = ok ? ssout[g] : 0.f;
        dA[tid] = ok ? 1.f / fmaxf((float)cnt_dst[g], 1.f) : 1.f;
        dB[tid] = ok ? 1.f / fmaxf((float)cnt_src[g], 1.f) : 1.f;
    }
    __syncthreads();
    const int og = tid & 31, ng = tid >> 5;
    const int o0 = og * 4, n0 = ng * 4;
    // stage 1: h_in = (y_in @ Ws2d + ss*b)/deg ; h_out likewise
    float ai[4][4] = {}, ao[4][4] = {};
    for (int w = 0; w < 64; w++){
        uint2 ws0 = *(const uint2*)(Wmsg + (2*w)   * 256 + o0);
        uint2 ws1 = *(const uint2*)(Wmsg + (2*w+1) * 256 + o0);
        uint2 wd0 = *(const uint2*)(Wmsg + (2*w)   * 256 + 128 + o0);
        uint2 wd1 = *(const uint2*)(Wmsg + (2*w+1) * 256 + 128 + o0);
        float s0[4] = {bf_lo(ws0.x), bf_hi(ws0.x), bf_lo(ws0.y), bf_hi(ws0.y)};
        float s1[4] = {bf_lo(ws1.x), bf_hi(ws1.x), bf_lo(ws1.y), bf_hi(ws1.y)};
        float d0[4] = {bf_lo(wd0.x), bf_hi(wd0.x), bf_lo(wd0.y), bf_hi(wd0.y)};
        float d1[4] = {bf_lo(wd1.x), bf_hi(wd1.x), bf_lo(wd1.y), bf_hi(wd1.y)};
        #pragma unroll
        for (int j = 0; j < 4; j++){
            u32 yi = ysh[n0 + j][w], yo = ysh[n0 + j][64 + w];
            float yi0 = bf_lo(yi), yi1 = bf_hi(yi), yo0 = bf_lo(yo), yo1 = bf_hi(yo);
            #pragma unroll
            for (int i = 0; i < 4; i++){
                ai[j][i] += yi0 * s0[i] + yi1 * s1[i];
                ao[j][i] += yo0 * d0[i] + yo1 * d1[i];
            }
        }
    }
    float4 bs = *(const float4*)(b_s2d + o0);
    float4 bd = *(const float4*)(b_d2s + o0);
    float bsv[4] = {bs.x, bs.y, bs.z, bs.w};
    float bdv[4] = {bd.x, bd.y, bd.z, bd.w};
    #pragma unroll
    for (int j = 0; j < 4; j++){
        int n = n0 + j;
        #pragma unroll
        for (int i = 0; i < 4; i++){
            gin[n * 256 + o0 + i]       = (ai[j][i] + sA[n] * bsv[i]) * dA[n];
            gin[n * 256 + 128 + o0 + i] = (ao[j][i] + sB[n] * bdv[i]) * dB[n];
        }
    }
    __syncthreads();
    // stage 2: gate MLP
    float acc[4][4] = {};
    for (int k = 0; k < 256; k++){
        uint2 wv = *(const uint2*)(Wg1b + k * 128 + o0);
        float wf0 = bf_lo(wv.x), wf1 = bf_hi(wv.x), wf2 = bf_lo(wv.y), wf3 = bf_hi(wv.y);
        #pragma unroll
        for (int j = 0; j < 4; j++){
            float xv = gin[(n0 + j) * 256 + k];
            acc[j][0] += xv * wf0; acc[j][1] += xv * wf1;
            acc[j][2] += xv * wf2; acc[j][3] += xv * wf3;
        }
    }
    float bg[4], w2[4];
    #pragma unroll
    for (int i = 0; i < 4; i++){ bg[i] = b_g1[o0 + i]; w2[i] = w_g2[o0 + i]; }
    #pragma unroll
    for (int j = 0; j < 4; j++){
        float p = 0.f;
        #pragma unroll
        for (int i = 0; i < 4; i++) p += fmaxf(acc[j][i] + bg[i], 0.f) * w2[i];
        part[(n0 + j) * 33 + og] = p;
    }
    __syncthreads();
    if (tid < 32){
        float s = 0.f;
        for (int i = 0; i < 32; i++) s += part[tid * 33 + i];
        gl[tid] = 1.f / (1.f + __expf(-(s + b_g2[0])));
    }
    __syncthreads();
    #pragma unroll
    for (int i = 0; i < 16; i++){
        int li = tid + i * 256;
        int nn = li >> 7, o = li & 127;
        int g = nb + nn;
        if (g < N_NODES){
            float gv = gl[nn];
            float hi = gin[nn * 256 + o], ho = gin[nn * 256 + 128 + o];
            out[g * 128 + o] = gv * hi + (1.f - gv) * ho + x[g * 128 + o];
        }
    }
}

extern "C" void kernel_launch(void* const* d_in, const int* in_sizes, int n_in,
                              void* d_out, int out_size, void* d_ws, size_t ws_size,
                              hipStream_t stream){
    const float* x     = (const float*)d_in[0];
    const int*   ei    = (const int*)d_in[1];          // int32 (JAX x64 off)
    const float* w_s2d = (const float*)d_in[2];
    const float* b_s2d = (const float*)d_in[3];
    const float* w_d2s = (const float*)d_in[4];
    const float* b_d2s = (const float*)d_in[5];
    const float* w_e1  = (const float*)d_in[6];
    const float* b_e1  = (const float*)d_in[7];
    const float* w_e2  = (const float*)d_in[8];
    const float* b_e2  = (const float*)d_in[9];
    const float* w_g1  = (const float*)d_in[10];
    const float* b_g1  = (const float*)d_in[11];
    const float* w_g2  = (const float*)d_in[12];
    const float* b_g2  = (const float*)d_in[13];
    float* out = (float*)d_out;
    u32*   T1  = (u32*)d_out;        // fp8 [A|B], 12.8 MB (overwritten later by Y)
    u32*   Y   = (u32*)d_out;        // bf16 [y_in|y_out], 25.6 MB

    char* ws = (char*)d_ws;
    size_t off = 0;
    #define TAKE(name, bytes) char* name = ws + off; off += (((size_t)(bytes)) + 511) & ~(size_t)511;
    TAKE(Wcat1_b, 32768 * 2)
    TAKE(Wmsg_b,  32768 * 2)
    TAKE(Wg1b_b,  32768 * 2)
    TAKE(bias1_b, 256 * 4)
    TAKE(xb_b,    (size_t)N_NODES * 128 * 2)  // x in bf16, 12.8 MB
    TAKE(score_b, (size_t)N_EDGES * 2)
    TAKE(cnt_b,   (size_t)2 * N_NODES * 4)    // cnt_dst | cnt_src
    TAKE(sd_b,    (size_t)N_NODES * 4)
    TAKE(ss_b,    (size_t)N_NODES * 4)
    TAKE(nd_b,    (size_t)N_NODES * 4)
    TAKE(ns_b,    (size_t)N_NODES * 4)
    TAKE(ipay_b,  (size_t)N_EDGES * 4)
    TAKE(opay_b,  (size_t)N_EDGES * 4)
    TAKE(ssin_b,  (size_t)N_NODES * 4)
    TAKE(ssout_b, (size_t)N_NODES * 4)
    #undef TAKE
    (void)ws_size; (void)in_sizes; (void)n_in; (void)out_size;
    // total ~22.6 MB

    zero_cnt_kernel<<<(2 * N_NODES + 1023) / 1024, 1024, 0, stream>>>((u32*)cnt_b);
    prep_kernel<<<(98560 + 255) / 256, 256, 0, stream>>>(w_s2d, w_d2s, w_e1, w_g1, b_e1,
        (u16*)Wcat1_b, (u16*)Wmsg_b, (u16*)Wg1b_b, (float*)bias1_b);
    xcast_kernel<<<(N_NODES * 64 + 255) / 256, 256, 0, stream>>>(x, (u32*)xb_b);
    proj_kernel<<<(N_NODES + 31) / 32, 256, 0, stream>>>(x, (const u16*)Wcat1_b, (const float*)bias1_b, T1);
    edge_score_kernel<<<N_EDGES / 4, 256, 0, stream>>>((const u16*)T1, ei, w_e2, b_e2,
        (u16*)score_b, (u32*)cnt_b, (u32*)cnt_b + N_NODES);
    scan_kernel<<<2, 1024, 0, stream>>>((const u32*)cnt_b, (u32*)sd_b, (u32*)nd_b, (u32*)ss_b, (u32*)ns_b);
    scatter_kernel<<<N_EDGES / 256, 256, 0, stream>>>(ei, (const u16*)score_b,
        (u32*)nd_b, (u32*)ns_b, (u32*)ipay_b, (u32*)opay_b);
    gather_kernel<<<N_NODES / 4, 256, 0, stream>>>((const u32*)xb_b,
        (const u32*)ipay_b, (const u32*)opay_b,
        (const u32*)cnt_b, (const u32*)sd_b, (const u32*)cnt_b + N_NODES, (const u32*)ss_b,
        Y, (float*)ssin_b, (float*)ssout_b);
    finale_kernel<<<(N_NODES + 31) / 32, 256, 0, stream>>>((const u32*)Y, x,
        (const u16*)Wmsg_b, b_s2d, b_d2s,
        (const float*)ssin_b, (const float*)ssout_b,
        (const u32*)cnt_b, (const u32*)cnt_b + N_NODES,
        (const u16*)Wg1b_b, b_g1, w_g2, b_g2, out);
}

// Round 5
// 579.578 us; speedup vs baseline: 1.3176x; 1.3176x over previous
//
#include <hip/hip_runtime.h>

#define N_NODES 50000
#define N_EDGES 800000

typedef unsigned int u32;
typedef unsigned short u16;
typedef __attribute__((ext_vector_type(2))) float float2v;
typedef __attribute__((ext_vector_type(8))) short bf16x8;
typedef __attribute__((ext_vector_type(4))) float f32x4;

__device__ __forceinline__ float bf_lo(u32 v){ return __uint_as_float(v << 16); }
__device__ __forceinline__ float bf_hi(u32 v){ return __uint_as_float(v & 0xffff0000u); }
__device__ __forceinline__ u16 f2bf(float f){
    u32 u = __float_as_uint(f);
    u += 0x7fffu + ((u >> 16) & 1u);     // round-to-nearest-even
    return (u16)(u >> 16);
}

#if __has_builtin(__builtin_amdgcn_cvt_pk_f32_fp8) && __has_builtin(__builtin_amdgcn_cvt_pk_fp8_f32)
#define HW_FP8 1
#else
#define HW_FP8 0
#endif

__device__ __forceinline__ u32 enc1_e4m3(float f){
    u32 u = __float_as_uint(f);
    u32 s = (u >> 24) & 0x80u;
    u32 a = u & 0x7fffffffu;
    if (a >= 0x43e00000u) return s | 0x7eu;          // >= 448 -> sat
    if (a < 0x3c800000u){                            // < 2^-6 -> denormal (m * 2^-9)
        float af = __uint_as_float(a) * 512.f;
        u32 m = (u32)(af + 0.5f);
        return s | m;
    }
    int e = (int)(a >> 23) - 127;
    u32 mant = (a >> 20) & 7u;
    u32 rnd = (a >> 19) & 1u;
    u32 sticky = (a & 0x7ffffu) ? 1u : 0u;
    u32 code = ((u32)(e + 7) << 3) | mant;
    code += (rnd & (sticky | (mant & 1u)));
    if (code > 0x7eu) code = 0x7eu;
    return s | code;
}

__device__ __forceinline__ float2v dec2_e4m3(u32 v16){
#if HW_FP8
    return __builtin_amdgcn_cvt_pk_f32_fp8(v16, false);
#else
    float2v r;
    #pragma unroll
    for (int t = 0; t < 2; t++){
        u32 b = (v16 >> (8 * t)) & 0xffu;
        u32 e = (b >> 3) & 15u, m = b & 7u;
        float v = e ? __uint_as_float(((e + 120u) << 23) | (m << 20)) : (float)m * 0.001953125f;
        r[t] = (b & 0x80u) ? -v : v;
    }
    return r;
#endif
}
__device__ __forceinline__ u32 encpk_lo(float a, float b, u32 old){
#if HW_FP8
    return (u32)__builtin_amdgcn_cvt_pk_fp8_f32(a, b, (int)old, false);
#else
    return (old & 0xffff0000u) | enc1_e4m3(a) | (enc1_e4m3(b) << 8);
#endif
}
__device__ __forceinline__ u32 encpk_hi(float a, float b, u32 old){
#if HW_FP8
    return (u32)__builtin_amdgcn_cvt_pk_fp8_f32(a, b, (int)old, true);
#else
    return (old & 0x0000ffffu) | (enc1_e4m3(a) << 16) | (enc1_e4m3(b) << 24);
#endif
}

// ---------------------------------------------------------------- zero counts
__global__ void zero_cnt_kernel(u32* __restrict__ cnt){
    int i = blockIdx.x * 1024 + threadIdx.x;
    if (i < 2 * N_NODES) cnt[i] = 0u;
}

// --------------------------- pack weights to bf16 MFMA A-fragment layout
// pk[((ks*NCH + ch)*4 + g)*8 + j] = W[k = ks*32 + g*8 + j][ch]
// pk1: NCH=256, W[k][ch] = ch<128 ? w_e1[k][ch] : w_e1[128+k][ch-128]   (score A|B)
// pkM: NCH=256, W[k][ch] = ch<128 ? w_s2d[k][ch] : w_d2s[k][ch-128]     (messages)
// pkG: NCH=128, K=256,     W[k][oc] = w_g1[k][oc]                        (gate)
__global__ void prep_kernel(const float* __restrict__ w_s2d, const float* __restrict__ w_d2s,
                            const float* __restrict__ w_e1, const float* __restrict__ w_g1,
                            const float* __restrict__ b_e1,
                            u16* __restrict__ pk1, u16* __restrict__ pkM,
                            u16* __restrict__ pkG, float* __restrict__ bias1){
    int idx = blockIdx.x * 256 + threadIdx.x;
    if (idx < 32768){
        int j = idx & 7, g = (idx >> 3) & 3, ch = (idx >> 5) & 255, ks = idx >> 13;
        int k = ks * 32 + g * 8 + j;
        float v = (ch < 128) ? w_e1[k * 128 + ch] : w_e1[(128 + k) * 128 + (ch - 128)];
        pk1[idx] = f2bf(v);
    } else if (idx < 65536){
        int i2 = idx - 32768;
        int j = i2 & 7, g = (i2 >> 3) & 3, ch = (i2 >> 5) & 255, ks = i2 >> 13;
        int k = ks * 32 + g * 8 + j;
        float v = (ch < 128) ? w_s2d[k * 128 + ch] : w_d2s[k * 128 + (ch - 128)];
        pkM[i2] = f2bf(v);
    } else if (idx < 98304){
        int i2 = idx - 65536;
        int j = i2 & 7, g = (i2 >> 3) & 3, oc = (i2 >> 5) & 127, ks = i2 >> 12;
        int k = ks * 32 + g * 8 + j;
        pkG[i2] = f2bf(w_g1[k * 128 + oc]);
    } else if (idx < 98560){
        int o = idx - 98304;
        bias1[o] = (o < 128) ? b_e1[o] : 0.f;
    }
}

// ------------------------------------------------------------- x -> bf16 copy
__global__ void xcast_kernel(const float* __restrict__ x, u32* __restrict__ xb){
    int i = blockIdx.x * 256 + threadIdx.x;      // one u32 (2 elems) per thread
    if (i < N_NODES * 64){
        float2 v = ((const float2*)x)[i];
        xb[i] = (u32)f2bf(v.x) | ((u32)f2bf(v.y) << 16);
    }
}

// ----------------------- score projections T1 = [A|B] fp8, via MFMA
// computes D^T = Wcat1^T @ X^T : lane holds node = n0+(l&15), ch = ch0+(l>>4)*4+r
__global__ __launch_bounds__(256) void proj_mfma_kernel(const u16* __restrict__ xb16,
        const u16* __restrict__ pk1, const float* __restrict__ bias1, u32* __restrict__ T1){
    const int tid = threadIdx.x;
    const int w = tid >> 6, l = tid & 63;
    const int l16 = l & 15, lg = l >> 4;
    const int n0 = blockIdx.x * 16;
    const int node = n0 + l16;
    bf16x8 bx[4];
    #pragma unroll
    for (int ks = 0; ks < 4; ks++)
        bx[ks] = *(const bf16x8*)(xb16 + node * 128 + ks * 32 + lg * 8);
    #pragma unroll
    for (int ct = 0; ct < 4; ct++){
        const int ch0 = w * 64 + ct * 16;
        f32x4 acc = {0.f, 0.f, 0.f, 0.f};
        #pragma unroll
        for (int ks = 0; ks < 4; ks++){
            bf16x8 a = *(const bf16x8*)(pk1 + ((ks * 256 + ch0 + l16) * 4 + lg) * 8);
            acc = __builtin_amdgcn_mfma_f32_16x16x32_bf16(a, bx[ks], acc, 0, 0, 0);
        }
        const int chb = ch0 + lg * 4;
        float f0 = acc[0] + bias1[chb],     f1 = acc[1] + bias1[chb + 1];
        float f2 = acc[2] + bias1[chb + 2], f3 = acc[3] + bias1[chb + 3];
        u32 wd = encpk_lo(f0, f1, 0u);
        wd = encpk_hi(f2, f3, wd);
        T1[node * 64 + (chb >> 2)] = wd;
    }
}

// ------------------------------------------- edge scores + degree histograms
__global__ __launch_bounds__(256) void edge_score_kernel(const u16* __restrict__ T1, const int* __restrict__ eidx,
        const float* __restrict__ w_e2, const float* __restrict__ b_e2,
        u16* __restrict__ score, u32* __restrict__ cnt_dst, u32* __restrict__ cnt_src){
    const int wave = threadIdx.x >> 6, lane = threadIdx.x & 63;
    const int e = blockIdx.x * 4 + wave;
    if (e >= N_EDGES) return;
    const int src = eidx[e];
    const int dst = eidx[N_EDGES + e];
    const u32 a16 = T1[src * 128 + lane];          // fp8 elems 2l,2l+1 of A
    const u32 b16 = T1[dst * 128 + 64 + lane];     // fp8 elems 2l,2l+1 of B
    float2v fa = dec2_e4m3(a16);
    float2v fb = dec2_e4m3(b16);
    const float2 w = ((const float2*)w_e2)[lane];
    float h0 = fmaxf(fa[0] + fb[0], 0.f);
    float h1 = fmaxf(fa[1] + fb[1], 0.f);
    float p = h0 * w.x + h1 * w.y;
    #pragma unroll
    for (int m = 32; m >= 1; m >>= 1) p += __shfl_xor(p, m, 64);
    if (lane == 0){
        float sc = 1.f / (1.f + __expf(-(p + b_e2[0])));
        score[e] = f2bf(sc);
        atomicAdd(cnt_dst + dst, 1u);
        atomicAdd(cnt_src + src, 1u);
    }
}

// ------------------------------------------------------- exclusive scan (x2)
__global__ __launch_bounds__(1024) void scan_kernel(const u32* __restrict__ cnt,
        u32* __restrict__ start_dst, u32* __restrict__ next_dst,
        u32* __restrict__ start_src, u32* __restrict__ next_src){
    __shared__ u32 sa[1024], sb[1024];
    const int t = threadIdx.x;
    const u32* c = cnt + (blockIdx.x ? N_NODES : 0);
    u32* st = blockIdx.x ? start_src : start_dst;
    u32* nx = blockIdx.x ? next_src  : next_dst;
    const int CH = 49;                       // 1024*49 = 50176 >= N
    const int base = t * CH;
    u32 s = 0;
    for (int j = 0; j < CH; j++){ int i = base + j; if (i < N_NODES) s += c[i]; }
    sa[t] = s; __syncthreads();
    u32* a = sa; u32* b = sb;
    for (int off = 1; off < 1024; off <<= 1){
        u32 v = a[t];
        if (t >= off) v += a[t - off];
        b[t] = v;
        __syncthreads();
        u32* tmp = a; a = b; b = tmp;
    }
    u32 run = (t == 0) ? 0u : a[t - 1];
    for (int j = 0; j < CH; j++){
        int i = base + j;
        if (i < N_NODES){ st[i] = run; nx[i] = run; run += c[i]; }
    }
}

// ------------------------------------------------- scatter edge payloads CSR
// payload u32: [score bf16 in high 16 | neighbor id in low 16]  (N < 65536)
__global__ __launch_bounds__(256) void scatter_kernel(const int* __restrict__ eidx, const u16* __restrict__ score,
        u32* __restrict__ next_dst, u32* __restrict__ next_src,
        u32* __restrict__ in_pay, u32* __restrict__ out_pay){
    int e = blockIdx.x * 256 + threadIdx.x;
    if (e >= N_EDGES) return;
    int src = eidx[e], dst = eidx[N_EDGES + e];
    u32 sc = (u32)score[e] << 16;
    u32 p1 = atomicAdd(next_dst + dst, 1u);
    in_pay[p1] = sc | (u32)src;
    u32 p2 = atomicAdd(next_src + src, 1u);
    out_pay[p2] = sc | (u32)dst;
}

// --------------------------------- gather weighted raw-x sums (both dirs)
// Y row (d_out as u32): words 0..63 = y_in (bf16 pair), 64..127 = y_out
__global__ __launch_bounds__(256) void gather_kernel(const u32* __restrict__ xb,
        const u32* __restrict__ in_pay, const u32* __restrict__ out_pay,
        const u32* __restrict__ cnt_dst, const u32* __restrict__ start_dst,
        const u32* __restrict__ cnt_src, const u32* __restrict__ start_src,
        u32* __restrict__ Y, float* __restrict__ ssin, float* __restrict__ ssout){
    const int wave = threadIdx.x >> 6, lane = threadIdx.x & 63;
    const int node = blockIdx.x * 4 + wave;
    if (node >= N_NODES) return;
    {
        u32 deg = cnt_dst[node], st = start_dst[node];
        float a0 = 0.f, a1 = 0.f, ss = 0.f;
        u32 j = 0;
        for (; j + 4 <= deg; j += 4){
            u32 p0 = in_pay[st+j], p1 = in_pay[st+j+1], p2 = in_pay[st+j+2], p3 = in_pay[st+j+3];
            u32 v0 = xb[(p0 & 0xffffu)*64 + lane], v1 = xb[(p1 & 0xffffu)*64 + lane];
            u32 v2 = xb[(p2 & 0xffffu)*64 + lane], v3 = xb[(p3 & 0xffffu)*64 + lane];
            float s0 = __uint_as_float(p0 & 0xffff0000u), s1 = __uint_as_float(p1 & 0xffff0000u);
            float s2 = __uint_as_float(p2 & 0xffff0000u), s3 = __uint_as_float(p3 & 0xffff0000u);
            a0 += s0*bf_lo(v0) + s1*bf_lo(v1) + s2*bf_lo(v2) + s3*bf_lo(v3);
            a1 += s0*bf_hi(v0) + s1*bf_hi(v1) + s2*bf_hi(v2) + s3*bf_hi(v3);
            ss += s0 + s1 + s2 + s3;
        }
        for (; j < deg; j++){
            u32 pl = in_pay[st + j];
            u32 v = xb[(pl & 0xffffu)*64 + lane];
            float sc = __uint_as_float(pl & 0xffff0000u);
            a0 += sc * bf_lo(v); a1 += sc * bf_hi(v); ss += sc;
        }
        Y[node * 128 + lane] = (u32)f2bf(a0) | ((u32)f2bf(a1) << 16);
        if (lane == 0) ssin[node] = ss;
    }
    {
        u32 deg = cnt_src[node], st = start_src[node];
        float a0 = 0.f, a1 = 0.f, ss = 0.f;
        u32 j = 0;
        for (; j + 4 <= deg; j += 4){
            u32 p0 = out_pay[st+j], p1 = out_pay[st+j+1], p2 = out_pay[st+j+2], p3 = out_pay[st+j+3];
            u32 v0 = xb[(p0 & 0xffffu)*64 + lane], v1 = xb[(p1 & 0xffffu)*64 + lane];
            u32 v2 = xb[(p2 & 0xffffu)*64 + lane], v3 = xb[(p3 & 0xffffu)*64 + lane];
            float s0 = __uint_as_float(p0 & 0xffff0000u), s1 = __uint_as_float(p1 & 0xffff0000u);
            float s2 = __uint_as_float(p2 & 0xffff0000u), s3 = __uint_as_float(p3 & 0xffff0000u);
            a0 += s0*bf_lo(v0) + s1*bf_lo(v1) + s2*bf_lo(v2) + s3*bf_lo(v3);
            a1 += s0*bf_hi(v0) + s1*bf_hi(v1) + s2*bf_hi(v2) + s3*bf_hi(v3);
            ss += s0 + s1 + s2 + s3;
        }
        for (; j < deg; j++){
            u32 pl = out_pay[st + j];
            u32 v = xb[(pl & 0xffffu)*64 + lane];
            float sc = __uint_as_float(pl & 0xffff0000u);
            a0 += sc * bf_lo(v); a1 += sc * bf_hi(v); ss += sc;
        }
        Y[node * 128 + 64 + lane] = (u32)f2bf(a0) | ((u32)f2bf(a1) << 16);
        if (lane == 0) ssout[node] = ss;
    }
}

// ------------- finale: msg GEMMs + normalize + gate MLP + fuse + residual
// all via MFMA; 16 nodes per block; Y lives in d_out and is overwritten by out
__global__ __launch_bounds__(256) void finale_mfma_kernel(const u32* __restrict__ Yw,
        const float* __restrict__ x,
        const u16* __restrict__ pkM, const u16* __restrict__ pkG,
        const float* __restrict__ b_s2d, const float* __restrict__ b_d2s,
        const float* __restrict__ ssin, const float* __restrict__ ssout,
        const u32* __restrict__ cnt_dst, const u32* __restrict__ cnt_src,
        const float* __restrict__ b_g1, const float* __restrict__ w_g2, const float* __restrict__ b_g2,
        float* __restrict__ out){
    __shared__ u32 Hsh[16][132];     // [node][256 ch as bf16 pairs] (+pad)
    __shared__ float part[16][17];
    __shared__ float gl[16];
    const int tid = threadIdx.x;
    const int w = tid >> 6, l = tid & 63;
    const int l16 = l & 15, lg = l >> 4;
    const int n0 = blockIdx.x * 16;
    const int node = n0 + l16;
    const int dir = w >> 1;          // 0: h_in(Ws2d,y_in), 1: h_out(Wd2s,y_out)
    const int cb = (w & 1) * 64;     // channel base within 128
    // ---- stage 1: H^T = Wmsg^T @ Y^T
    const u16* Yh = (const u16*)Yw;
    bf16x8 yf[4];
    #pragma unroll
    for (int ks = 0; ks < 4; ks++)
        yf[ks] = *(const bf16x8*)(Yh + node * 256 + dir * 128 + ks * 32 + lg * 8);
    const float ssv  = dir ? ssout[node] : ssin[node];
    const float dinv = 1.f / fmaxf((float)(dir ? cnt_src[node] : cnt_dst[node]), 1.f);
    const float* bv = dir ? b_d2s : b_s2d;
    #pragma unroll
    for (int ct = 0; ct < 4; ct++){
        const int chl = cb + ct * 16;             // within 128
        f32x4 acc = {0.f, 0.f, 0.f, 0.f};
        #pragma unroll
        for (int ks = 0; ks < 4; ks++){
            bf16x8 a = *(const bf16x8*)(pkM + ((ks * 256 + dir * 128 + chl + l16) * 4 + lg) * 8);
            acc = __builtin_amdgcn_mfma_f32_16x16x32_bf16(a, yf[ks], acc, 0, 0, 0);
        }
        const int chb = chl + lg * 4;             // within 128
        float h0 = (acc[0] + ssv * bv[chb])     * dinv;
        float h1 = (acc[1] + ssv * bv[chb + 1]) * dinv;
        float h2 = (acc[2] + ssv * bv[chb + 2]) * dinv;
        float h3 = (acc[3] + ssv * bv[chb + 3]) * dinv;
        const int wi = (dir * 128 + chb) >> 1;
        Hsh[l16][wi]     = (u32)f2bf(h0) | ((u32)f2bf(h1) << 16);
        Hsh[l16][wi + 1] = (u32)f2bf(h2) | ((u32)f2bf(h3) << 16);
    }
    __syncthreads();
    // ---- stage 2: U^T = Wg1^T @ gin^T  (gin = [h_in|h_out], K=256)
    bf16x8 hb[8];
    #pragma unroll
    for (int ks = 0; ks < 8; ks++)
        hb[ks] = *(const bf16x8*)((const u16*)&Hsh[l16][0] + ks * 32 + lg * 8);
    float p = 0.f;
    #pragma unroll
    for (int ct2 = 0; ct2 < 2; ct2++){
        const int oc0 = w * 32 + ct2 * 16;
        f32x4 acc = {0.f, 0.f, 0.f, 0.f};
        #pragma unroll
        for (int ks = 0; ks < 8; ks++){
            bf16x8 a = *(const bf16x8*)(pkG + ((ks * 128 + oc0 + l16) * 4 + lg) * 8);
            acc = __builtin_amdgcn_mfma_f32_16x16x32_bf16(a, hb[ks], acc, 0, 0, 0);
        }
        const int ob = oc0 + lg * 4;
        #pragma unroll
        for (int r = 0; r < 4; r++)
            p += fmaxf(acc[r] + b_g1[ob + r], 0.f) * w_g2[ob + r];
    }
    part[l16][w * 4 + lg] = p;
    __syncthreads();
    if (tid < 16){
        float s = 0.f;
        #pragma unroll
        for (int i = 0; i < 16; i++) s += part[tid][i];
        gl[tid] = 1.f / (1.f + __expf(-(s + b_g2[0])));
    }
    __syncthreads();
    // ---- fuse + residual (overwrites Y in d_out)
    {
        const int nn = tid >> 4, o = (tid & 15) * 8;
        const float gv = gl[nn];
        const int gbase = (n0 + nn) * 128 + o;
        float4 x0 = *(const float4*)(x + gbase);
        float4 x1 = *(const float4*)(x + gbase + 4);
        float r[8];
        #pragma unroll
        for (int t = 0; t < 4; t++){
            u32 hi = Hsh[nn][(o >> 1) + t];
            u32 ho = Hsh[nn][64 + (o >> 1) + t];
            r[2*t]   = gv * bf_lo(hi) + (1.f - gv) * bf_lo(ho);
            r[2*t+1] = gv * bf_hi(hi) + (1.f - gv) * bf_hi(ho);
        }
        *(float4*)(out + gbase)     = make_float4(r[0]+x0.x, r[1]+x0.y, r[2]+x0.z, r[3]+x0.w);
        *(float4*)(out + gbase + 4) = make_float4(r[4]+x1.x, r[5]+x1.y, r[6]+x1.z, r[7]+x1.w);
    }
}

extern "C" void kernel_launch(void* const* d_in, const int* in_sizes, int n_in,
                              void* d_out, int out_size, void* d_ws, size_t ws_size,
                              hipStream_t stream){
    const float* x     = (const float*)d_in[0];
    const int*   ei    = (const int*)d_in[1];          // int32 (JAX x64 off)
    const float* w_s2d = (const float*)d_in[2];
    const float* b_s2d = (const float*)d_in[3];
    const float* w_d2s = (const float*)d_in[4];
    const float* b_d2s = (const float*)d_in[5];
    const float* w_e1  = (const float*)d_in[6];
    const float* b_e1  = (const float*)d_in[7];
    const float* w_e2  = (const float*)d_in[8];
    const float* b_e2  = (const float*)d_in[9];
    const float* w_g1  = (const float*)d_in[10];
    const float* b_g1  = (const float*)d_in[11];
    const float* w_g2  = (const float*)d_in[12];
    const float* b_g2  = (const float*)d_in[13];
    float* out = (float*)d_out;
    u32*   T1  = (u32*)d_out;        // fp8 [A|B], 12.8 MB (overwritten later by Y)
    u32*   Y   = (u32*)d_out;        // bf16 [y_in|y_out], 25.6 MB

    char* ws = (char*)d_ws;
    size_t off = 0;
    #define TAKE(name, bytes) char* name = ws + off; off += (((size_t)(bytes)) + 511) & ~(size_t)511;
    TAKE(pk1_b,   32768 * 2)
    TAKE(pkM_b,   32768 * 2)
    TAKE(pkG_b,   32768 * 2)
    TAKE(bias1_b, 256 * 4)
    TAKE(xb_b,    (size_t)N_NODES * 128 * 2)  // x in bf16, 12.8 MB
    TAKE(score_b, (size_t)N_EDGES * 2)
    TAKE(cnt_b,   (size_t)2 * N_NODES * 4)    // cnt_dst | cnt_src
    TAKE(sd_b,    (size_t)N_NODES * 4)
    TAKE(ss_b,    (size_t)N_NODES * 4)
    TAKE(nd_b,    (size_t)N_NODES * 4)
    TAKE(ns_b,    (size_t)N_NODES * 4)
    TAKE(ipay_b,  (size_t)N_EDGES * 4)
    TAKE(opay_b,  (size_t)N_EDGES * 4)
    TAKE(ssin_b,  (size_t)N_NODES * 4)
    TAKE(ssout_b, (size_t)N_NODES * 4)
    #undef TAKE
    (void)ws_size; (void)in_sizes; (void)n_in; (void)out_size;
    // total ~22.6 MB

    zero_cnt_kernel<<<(2 * N_NODES + 1023) / 1024, 1024, 0, stream>>>((u32*)cnt_b);
    prep_kernel<<<(98560 + 255) / 256, 256, 0, stream>>>(w_s2d, w_d2s, w_e1, w_g1, b_e1,
        (u16*)pk1_b, (u16*)pkM_b, (u16*)pkG_b, (float*)bias1_b);
    xcast_kernel<<<(N_NODES * 64 + 255) / 256, 256, 0, stream>>>(x, (u32*)xb_b);
    proj_mfma_kernel<<<N_NODES / 16, 256, 0, stream>>>((const u16*)xb_b,
        (const u16*)pk1_b, (const float*)bias1_b, T1);
    edge_score_kernel<<<N_EDGES / 4, 256, 0, stream>>>((const u16*)T1, ei, w_e2, b_e2,
        (u16*)score_b, (u32*)cnt_b, (u32*)cnt_b + N_NODES);
    scan_kernel<<<2, 1024, 0, stream>>>((const u32*)cnt_b, (u32*)sd_b, (u32*)nd_b, (u32*)ss_b, (u32*)ns_b);
    scatter_kernel<<<N_EDGES / 256, 256, 0, stream>>>(ei, (const u16*)score_b,
        (u32*)nd_b, (u32*)ns_b, (u32*)ipay_b, (u32*)opay_b);
    gather_kernel<<<N_NODES / 4, 256, 0, stream>>>((const u32*)xb_b,
        (const u32*)ipay_b, (const u32*)opay_b,
        (const u32*)cnt_b, (const u32*)sd_b, (const u32*)cnt_b + N_NODES, (const u32*)ss_b,
        Y, (float*)ssin_b, (float*)ssout_b);
    finale_mfma_kernel<<<N_NODES / 16, 256, 0, stream>>>((const u32*)Y, x,
        (const u16*)pkM_b, (const u16*)pkG_b, b_s2d, b_d2s,
        (const float*)ssin_b, (const float*)ssout_b,
        (const u32*)cnt_b, (const u32*)cnt_b + N_NODES,
        b_g1, w_g2, b_g2, out);
}

// Round 7
// 475.055 us; speedup vs baseline: 1.6076x; 1.2200x over previous
//
#include <hip/hip_runtime.h>

#define N_NODES 50000
#define N_EDGES 800000

typedef unsigned int u32;
typedef unsigned short u16;
typedef __attribute__((ext_vector_type(2))) float float2v;
typedef __attribute__((ext_vector_type(8))) short bf16x8;
typedef __attribute__((ext_vector_type(4))) float f32x4;

__device__ __forceinline__ float bf_lo(u32 v){ return __uint_as_float(v << 16); }
__device__ __forceinline__ float bf_hi(u32 v){ return __uint_as_float(v & 0xffff0000u); }
__device__ __forceinline__ u16 f2bf(float f){
    u32 u = __float_as_uint(f);
    u += 0x7fffu + ((u >> 16) & 1u);     // round-to-nearest-even
    return (u16)(u >> 16);
}

#if __has_builtin(__builtin_amdgcn_cvt_pk_f32_fp8) && __has_builtin(__builtin_amdgcn_cvt_pk_fp8_f32)
#define HW_FP8 1
#else
#define HW_FP8 0
#endif

__device__ __forceinline__ u32 enc1_e4m3(float f){
    u32 u = __float_as_uint(f);
    u32 s = (u >> 24) & 0x80u;
    u32 a = u & 0x7fffffffu;
    if (a >= 0x43e00000u) return s | 0x7eu;          // >= 448 -> sat
    if (a < 0x3c800000u){                            // < 2^-6 -> denormal (m * 2^-9)
        float af = __uint_as_float(a) * 512.f;
        u32 m = (u32)(af + 0.5f);
        return s | m;
    }
    int e = (int)(a >> 23) - 127;
    u32 mant = (a >> 20) & 7u;
    u32 rnd = (a >> 19) & 1u;
    u32 sticky = (a & 0x7ffffu) ? 1u : 0u;
    u32 code = ((u32)(e + 7) << 3) | mant;
    code += (rnd & (sticky | (mant & 1u)));
    if (code > 0x7eu) code = 0x7eu;
    return s | code;
}

template<bool HI>
__device__ __forceinline__ float2v dec2_word(u32 v){
#if HW_FP8
    return __builtin_amdgcn_cvt_pk_f32_fp8(v, HI);
#else
    u32 v16 = HI ? (v >> 16) : (v & 0xffffu);
    float2v r;
    #pragma unroll
    for (int t = 0; t < 2; t++){
        u32 b = (v16 >> (8 * t)) & 0xffu;
        u32 e = (b >> 3) & 15u, m = b & 7u;
        float fv = e ? __uint_as_float(((e + 120u) << 23) | (m << 20)) : (float)m * 0.001953125f;
        r[t] = (b & 0x80u) ? -fv : fv;
    }
    return r;
#endif
}
__device__ __forceinline__ u32 encpk_lo(float a, float b, u32 old){
#if HW_FP8
    return (u32)__builtin_amdgcn_cvt_pk_fp8_f32(a, b, (int)old, false);
#else
    return (old & 0xffff0000u) | enc1_e4m3(a) | (enc1_e4m3(b) << 8);
#endif
}
__device__ __forceinline__ u32 encpk_hi(float a, float b, u32 old){
#if HW_FP8
    return (u32)__builtin_amdgcn_cvt_pk_fp8_f32(a, b, (int)old, true);
#else
    return (old & 0x0000ffffu) | (enc1_e4m3(a) << 16) | (enc1_e4m3(b) << 24);
#endif
}

// ---------------------------------------------------------------- zero counts
__global__ void zero_cnt_kernel(u32* __restrict__ cnt){
    int i = blockIdx.x * 1024 + threadIdx.x;
    if (i < 2 * N_NODES) cnt[i] = 0u;
}

// --------------------------- pack weights to bf16 MFMA A-fragment layout
// pk[((ks*NCH + ch)*4 + g)*8 + j] = W[k = ks*32 + g*8 + j][ch]
__global__ void prep_kernel(const float* __restrict__ w_s2d, const float* __restrict__ w_d2s,
                            const float* __restrict__ w_e1, const float* __restrict__ w_g1,
                            const float* __restrict__ b_e1,
                            u16* __restrict__ pk1, u16* __restrict__ pkM,
                            u16* __restrict__ pkG, float* __restrict__ bias1){
    int idx = blockIdx.x * 256 + threadIdx.x;
    if (idx < 32768){
        int j = idx & 7, g = (idx >> 3) & 3, ch = (idx >> 5) & 255, ks = idx >> 13;
        int k = ks * 32 + g * 8 + j;
        float v = (ch < 128) ? w_e1[k * 128 + ch] : w_e1[(128 + k) * 128 + (ch - 128)];
        pk1[idx] = f2bf(v);
    } else if (idx < 65536){
        int i2 = idx - 32768;
        int j = i2 & 7, g = (i2 >> 3) & 3, ch = (i2 >> 5) & 255, ks = i2 >> 13;
        int k = ks * 32 + g * 8 + j;
        float v = (ch < 128) ? w_s2d[k * 128 + ch] : w_d2s[k * 128 + (ch - 128)];
        pkM[i2] = f2bf(v);
    } else if (idx < 98304){
        int i2 = idx - 65536;
        int j = i2 & 7, g = (i2 >> 3) & 3, oc = (i2 >> 5) & 127, ks = i2 >> 12;
        int k = ks * 32 + g * 8 + j;
        pkG[i2] = f2bf(w_g1[k * 128 + oc]);
    } else if (idx < 98560){
        int o = idx - 98304;
        bias1[o] = (o < 128) ? b_e1[o] : 0.f;
    }
}

// ------------------------------------------------------------- x -> bf16 copy
__global__ void xcast_kernel(const float* __restrict__ x, u32* __restrict__ xb){
    int i = blockIdx.x * 256 + threadIdx.x;      // one u32 (2 elems) per thread
    if (i < N_NODES * 64){
        float2 v = ((const float2*)x)[i];
        xb[i] = (u32)f2bf(v.x) | ((u32)f2bf(v.y) << 16);
    }
}

// ----------------------- score projections T1 = [A|B] fp8, via MFMA
__global__ __launch_bounds__(256) void proj_mfma_kernel(const u16* __restrict__ xb16,
        const u16* __restrict__ pk1, const float* __restrict__ bias1, u32* __restrict__ T1){
    const int tid = threadIdx.x;
    const int w = tid >> 6, l = tid & 63;
    const int l16 = l & 15, lg = l >> 4;
    const int n0 = blockIdx.x * 16;
    const int node = n0 + l16;
    bf16x8 bx[4];
    #pragma unroll
    for (int ks = 0; ks < 4; ks++)
        bx[ks] = *(const bf16x8*)(xb16 + node * 128 + ks * 32 + lg * 8);
    #pragma unroll
    for (int ct = 0; ct < 4; ct++){
        const int ch0 = w * 64 + ct * 16;
        f32x4 acc = {0.f, 0.f, 0.f, 0.f};
        #pragma unroll
        for (int ks = 0; ks < 4; ks++){
            bf16x8 a = *(const bf16x8*)(pk1 + ((ks * 256 + ch0 + l16) * 4 + lg) * 8);
            acc = __builtin_amdgcn_mfma_f32_16x16x32_bf16(a, bx[ks], acc, 0, 0, 0);
        }
        const int chb = ch0 + lg * 4;
        float f0 = acc[0] + bias1[chb],     f1 = acc[1] + bias1[chb + 1];
        float f2 = acc[2] + bias1[chb + 2], f3 = acc[3] + bias1[chb + 3];
        u32 wd = encpk_lo(f0, f1, 0u);
        wd = encpk_hi(f2, f3, wd);
        T1[node * 64 + (chb >> 2)] = wd;
    }
}

// ------------------------------------------- edge scores + degree histograms
// 16 lanes per edge; each lane covers 8 channels (8 fp8 bytes = one dwordx2)
__global__ __launch_bounds__(256) void edge_score_kernel(const u32* __restrict__ T1w, const int* __restrict__ eidx,
        const float* __restrict__ w_e2, const float* __restrict__ b_e2,
        u16* __restrict__ score, u32* __restrict__ cnt_dst, u32* __restrict__ cnt_src){
    const int l16 = threadIdx.x & 15;
    const int e = blockIdx.x * 16 + (threadIdx.x >> 4);
    const int src = eidx[e];
    const int dst = eidx[N_EDGES + e];
    // T1 row = 64 u32 (256 fp8 bytes): A = words 0..31, B = words 32..63
    const uint2 a8 = *(const uint2*)(T1w + src * 64 + l16 * 2);
    const uint2 b8 = *(const uint2*)(T1w + dst * 64 + 32 + l16 * 2);
    float2v a0 = dec2_word<false>(a8.x), a1 = dec2_word<true>(a8.x);
    float2v a2 = dec2_word<false>(a8.y), a3 = dec2_word<true>(a8.y);
    float2v b0 = dec2_word<false>(b8.x), b1 = dec2_word<true>(b8.x);
    float2v b2 = dec2_word<false>(b8.y), b3 = dec2_word<true>(b8.y);
    const float4 w0 = ((const float4*)w_e2)[l16 * 2];
    const float4 w1 = ((const float4*)w_e2)[l16 * 2 + 1];
    float p = fmaxf(a0[0] + b0[0], 0.f) * w0.x + fmaxf(a0[1] + b0[1], 0.f) * w0.y
            + fmaxf(a1[0] + b1[0], 0.f) * w0.z + fmaxf(a1[1] + b1[1], 0.f) * w0.w
            + fmaxf(a2[0] + b2[0], 0.f) * w1.x + fmaxf(a2[1] + b2[1], 0.f) * w1.y
            + fmaxf(a3[0] + b3[0], 0.f) * w1.z + fmaxf(a3[1] + b3[1], 0.f) * w1.w;
    p += __shfl_xor(p, 1, 64);
    p += __shfl_xor(p, 2, 64);
    p += __shfl_xor(p, 4, 64);
    p += __shfl_xor(p, 8, 64);
    if (l16 == 0){
        float sc = 1.f / (1.f + __expf(-(p + b_e2[0])));
        score[e] = f2bf(sc);
        atomicAdd(cnt_dst + dst, 1u);
        atomicAdd(cnt_src + src, 1u);
    }
}

// ------------------------------------------------------- exclusive scan (x2)
__global__ __launch_bounds__(1024) void scan_kernel(const u32* __restrict__ cnt,
        u32* __restrict__ start_dst, u32* __restrict__ next_dst,
        u32* __restrict__ start_src, u32* __restrict__ next_src){
    __shared__ u32 sa[1024], sb[1024];
    const int t = threadIdx.x;
    const u32* c = cnt + (blockIdx.x ? N_NODES : 0);
    u32* st = blockIdx.x ? start_src : start_dst;
    u32* nx = blockIdx.x ? next_src  : next_dst;
    const int CH = 49;                       // 1024*49 = 50176 >= N
    const int base = t * CH;
    u32 s = 0;
    for (int j = 0; j < CH; j++){ int i = base + j; if (i < N_NODES) s += c[i]; }
    sa[t] = s; __syncthreads();
    u32* a = sa; u32* b = sb;
    for (int off = 1; off < 1024; off <<= 1){
        u32 v = a[t];
        if (t >= off) v += a[t - off];
        b[t] = v;
        __syncthreads();
        u32* tmp = a; a = b; b = tmp;
    }
    u32 run = (t == 0) ? 0u : a[t - 1];
    for (int j = 0; j < CH; j++){
        int i = base + j;
        if (i < N_NODES){ st[i] = run; nx[i] = run; run += c[i]; }
    }
}

// ------------------------------------------------- scatter edge payloads CSR
// payload u32: [score bf16 in high 16 | neighbor id in low 16]  (N < 65536)
__global__ __launch_bounds__(256) void scatter_kernel(const int* __restrict__ eidx, const u16* __restrict__ score,
        u32* __restrict__ next_dst, u32* __restrict__ next_src,
        u32* __restrict__ in_pay, u32* __restrict__ out_pay){
    int e = blockIdx.x * 256 + threadIdx.x;
    if (e >= N_EDGES) return;
    int src = eidx[e], dst = eidx[N_EDGES + e];
    u32 sc = (u32)score[e] << 16;
    u32 p1 = atomicAdd(next_dst + dst, 1u);
    in_pay[p1] = sc | (u32)src;
    u32 p2 = atomicAdd(next_src + src, 1u);
    out_pay[p2] = sc | (u32)dst;
}

// --------------------------------- gather weighted raw-x sums (both dirs)
// one wave per (node, direction); Y row: words 0..63 = y_in, 64..127 = y_out
__global__ __launch_bounds__(256) void gather_kernel(const u32* __restrict__ xb,
        const u32* __restrict__ in_pay, const u32* __restrict__ out_pay,
        const u32* __restrict__ cnt_dst, const u32* __restrict__ start_dst,
        const u32* __restrict__ cnt_src, const u32* __restrict__ start_src,
        u32* __restrict__ Y, float* __restrict__ ssin, float* __restrict__ ssout){
    const int w = threadIdx.x >> 6, lane = threadIdx.x & 63;
    const int node = blockIdx.x * 2 + (w >> 1);
    const int dir = w & 1;
    const u32* __restrict__ pay = dir ? out_pay : in_pay;
    const u32 deg = dir ? cnt_src[node] : cnt_dst[node];
    const u32 st  = dir ? start_src[node] : start_dst[node];
    float a0 = 0.f, a1 = 0.f, ss = 0.f;
    u32 j = 0;
    for (; j + 4 <= deg; j += 4){
        u32 p0 = pay[st+j], p1 = pay[st+j+1], p2 = pay[st+j+2], p3 = pay[st+j+3];
        u32 v0 = xb[(p0 & 0xffffu)*64 + lane], v1 = xb[(p1 & 0xffffu)*64 + lane];
        u32 v2 = xb[(p2 & 0xffffu)*64 + lane], v3 = xb[(p3 & 0xffffu)*64 + lane];
        float s0 = __uint_as_float(p0 & 0xffff0000u), s1 = __uint_as_float(p1 & 0xffff0000u);
        float s2 = __uint_as_float(p2 & 0xffff0000u), s3 = __uint_as_float(p3 & 0xffff0000u);
        a0 += s0*bf_lo(v0) + s1*bf_lo(v1) + s2*bf_lo(v2) + s3*bf_lo(v3);
        a1 += s0*bf_hi(v0) + s1*bf_hi(v1) + s2*bf_hi(v2) + s3*bf_hi(v3);
        ss += s0 + s1 + s2 + s3;
    }
    for (; j < deg; j++){
        u32 pl = pay[st + j];
        u32 v = xb[(pl & 0xffffu)*64 + lane];
        float sc = __uint_as_float(pl & 0xffff0000u);
        a0 += sc * bf_lo(v); a1 += sc * bf_hi(v); ss += sc;
    }
    Y[node * 128 + dir * 64 + lane] = (u32)f2bf(a0) | ((u32)f2bf(a1) << 16);
    if (lane == 0){
        if (dir) ssout[node] = ss; else ssin[node] = ss;
    }
}

// ------------- finale: msg GEMMs + normalize + gate MLP + fuse + residual
__global__ __launch_bounds__(256) void finale_mfma_kernel(const u32* __restrict__ Yw,
        const float* __restrict__ x,
        const u16* __restrict__ pkM, const u16* __restrict__ pkG,
        const float* __restrict__ b_s2d, const float* __restrict__ b_d2s,
        const float* __restrict__ ssin, const float* __restrict__ ssout,
        const u32* __restrict__ cnt_dst, const u32* __restrict__ cnt_src,
        const float* __restrict__ b_g1, const float* __restrict__ w_g2, const float* __restrict__ b_g2,
        float* __restrict__ out){
    __shared__ u32 Hsh[16][132];     // [node][256 ch as bf16 pairs] (+pad)
    __shared__ float part[16][17];
    __shared__ float gl[16];
    const int tid = threadIdx.x;
    const int w = tid >> 6, l = tid & 63;
    const int l16 = l & 15, lg = l >> 4;
    const int n0 = blockIdx.x * 16;
    const int node = n0 + l16;
    const int dir = w >> 1;          // 0: h_in(Ws2d,y_in), 1: h_out(Wd2s,y_out)
    const int cb = (w & 1) * 64;     // channel base within 128
    // ---- stage 1: H^T = Wmsg^T @ Y^T
    const u16* Yh = (const u16*)Yw;
    bf16x8 yf[4];
    #pragma unroll
    for (int ks = 0; ks < 4; ks++)
        yf[ks] = *(const bf16x8*)(Yh + node * 256 + dir * 128 + ks * 32 + lg * 8);
    const float ssv  = dir ? ssout[node] : ssin[node];
    const float dinv = 1.f / fmaxf((float)(dir ? cnt_src[node] : cnt_dst[node]), 1.f);
    const float* bv = dir ? b_d2s : b_s2d;
    #pragma unroll
    for (int ct = 0; ct < 4; ct++){
        const int chl = cb + ct * 16;             // within 128
        f32x4 acc = {0.f, 0.f, 0.f, 0.f};
        #pragma unroll
        for (int ks = 0; ks < 4; ks++){
            bf16x8 a = *(const bf16x8*)(pkM + ((ks * 256 + dir * 128 + chl + l16) * 4 + lg) * 8);
            acc = __builtin_amdgcn_mfma_f32_16x16x32_bf16(a, yf[ks], acc, 0, 0, 0);
        }
        const int chb = chl + lg * 4;             // within 128
        float h0 = (acc[0] + ssv * bv[chb])     * dinv;
        float h1 = (acc[1] + ssv * bv[chb + 1]) * dinv;
        float h2 = (acc[2] + ssv * bv[chb + 2]) * dinv;
        float h3 = (acc[3] + ssv * bv[chb + 3]) * dinv;
        const int wi = (dir * 128 + chb) >> 1;
        Hsh[l16][wi]     = (u32)f2bf(h0) | ((u32)f2bf(h1) << 16);
        Hsh[l16][wi + 1] = (u32)f2bf(h2) | ((u32)f2bf(h3) << 16);
    }
    __syncthreads();
    // ---- stage 2: U^T = Wg1^T @ gin^T  (gin = [h_in|h_out], K=256)
    bf16x8 hb[8];
    #pragma unroll
    for (int ks = 0; ks < 8; ks++)
        hb[ks] = *(const bf16x8*)((const u16*)&Hsh[l16][0] + ks * 32 + lg * 8);
    float p = 0.f;
    #pragma unroll
    for (int ct2 = 0; ct2 < 2; ct2++){
        const int oc0 = w * 32 + ct2 * 16;
        f32x4 acc = {0.f, 0.f, 0.f, 0.f};
        #pragma unroll
        for (int ks = 0; ks < 8; ks++){
            bf16x8 a = *(const bf16x8*)(pkG + ((ks * 128 + oc0 + l16) * 4 + lg) * 8);
            acc = __builtin_amdgcn_mfma_f32_16x16x32_bf16(a, hb[ks], acc, 0, 0, 0);
        }
        const int ob = oc0 + lg * 4;
        #pragma unroll
        for (int r = 0; r < 4; r++)
            p += fmaxf(acc[r] + b_g1[ob + r], 0.f) * w_g2[ob + r];
    }
    part[l16][w * 4 + lg] = p;
    __syncthreads();
    if (tid < 16){
        float s = 0.f;
        #pragma unroll
        for (int i = 0; i < 16; i++) s += part[tid][i];
        gl[tid] = 1.f / (1.f + __expf(-(s + b_g2[0])));
    }
    __syncthreads();
    // ---- fuse + residual (overwrites Y in d_out)
    {
        const int nn = tid >> 4, o = (tid & 15) * 8;
        const float gv = gl[nn];
        const int gbase = (n0 + nn) * 128 + o;
        float4 x0 = *(const float4*)(x + gbase);
        float4 x1 = *(const float4*)(x + gbase + 4);
        float r[8];
        #pragma unroll
        for (int t = 0; t < 4; t++){
            u32 hi = Hsh[nn][(o >> 1) + t];
            u32 ho = Hsh[nn][64 + (o >> 1) + t];
            r[2*t]   = gv * bf_lo(hi) + (1.f - gv) * bf_lo(ho);
            r[2*t+1] = gv * bf_hi(hi) + (1.f - gv) * bf_hi(ho);
        }
        *(float4*)(out + gbase)     = make_float4(r[0]+x0.x, r[1]+x0.y, r[2]+x0.z, r[3]+x0.w);
        *(float4*)(out + gbase + 4) = make_float4(r[4]+x1.x, r[5]+x1.y, r[6]+x1.z, r[7]+x1.w);
    }
}

extern "C" void kernel_launch(void* const* d_in, const int* in_sizes, int n_in,
                              void* d_out, int out_size, void* d_ws, size_t ws_size,
                              hipStream_t stream){
    const float* x     = (const float*)d_in[0];
    const int*   ei    = (const int*)d_in[1];          // int32 (JAX x64 off)
    const float* w_s2d = (const float*)d_in[2];
    const float* b_s2d = (const float*)d_in[3];
    const float* w_d2s = (const float*)d_in[4];
    const float* b_d2s = (const float*)d_in[5];
    const float* w_e1  = (const float*)d_in[6];
    const float* b_e1  = (const float*)d_in[7];
    const float* w_e2  = (const float*)d_in[8];
    const float* b_e2  = (const float*)d_in[9];
    const float* w_g1  = (const float*)d_in[10];
    const float* b_g1  = (const float*)d_in[11];
    const float* w_g2  = (const float*)d_in[12];
    const float* b_g2  = (const float*)d_in[13];
    float* out = (float*)d_out;
    u32*   T1  = (u32*)d_out;        // fp8 [A|B], 12.8 MB (overwritten later by Y)
    u32*   Y   = (u32*)d_out;        // bf16 [y_in|y_out], 25.6 MB

    char* ws = (char*)d_ws;
    size_t off = 0;
    #define TAKE(name, bytes) char* name = ws + off; off += (((size_t)(bytes)) + 511) & ~(size_t)511;
    TAKE(pk1_b,   32768 * 2)
    TAKE(pkM_b,   32768 * 2)
    TAKE(pkG_b,   32768 * 2)
    TAKE(bias1_b, 256 * 4)
    TAKE(xb_b,    (size_t)N_NODES * 128 * 2)  // x in bf16, 12.8 MB
    TAKE(score_b, (size_t)N_EDGES * 2)
    TAKE(cnt_b,   (size_t)2 * N_NODES * 4)    // cnt_dst | cnt_src
    TAKE(sd_b,    (size_t)N_NODES * 4)
    TAKE(ss_b,    (size_t)N_NODES * 4)
    TAKE(nd_b,    (size_t)N_NODES * 4)
    TAKE(ns_b,    (size_t)N_NODES * 4)
    TAKE(ipay_b,  (size_t)N_EDGES * 4)
    TAKE(opay_b,  (size_t)N_EDGES * 4)
    TAKE(ssin_b,  (size_t)N_NODES * 4)
    TAKE(ssout_b, (size_t)N_NODES * 4)
    #undef TAKE
    (void)ws_size; (void)in_sizes; (void)n_in; (void)out_size;
    // total ~22.6 MB

    zero_cnt_kernel<<<(2 * N_NODES + 1023) / 1024, 1024, 0, stream>>>((u32*)cnt_b);
    prep_kernel<<<(98560 + 255) / 256, 256, 0, stream>>>(w_s2d, w_d2s, w_e1, w_g1, b_e1,
        (u16*)pk1_b, (u16*)pkM_b, (u16*)pkG_b, (float*)bias1_b);
    xcast_kernel<<<(N_NODES * 64 + 255) / 256, 256, 0, stream>>>(x, (u32*)xb_b);
    proj_mfma_kernel<<<N_NODES / 16, 256, 0, stream>>>((const u16*)xb_b,
        (const u16*)pk1_b, (const float*)bias1_b, T1);
    edge_score_kernel<<<N_EDGES / 16, 256, 0, stream>>>((const u32*)T1, ei, w_e2, b_e2,
        (u16*)score_b, (u32*)cnt_b, (u32*)cnt_b + N_NODES);
    scan_kernel<<<2, 1024, 0, stream>>>((const u32*)cnt_b, (u32*)sd_b, (u32*)nd_b, (u32*)ss_b, (u32*)ns_b);
    scatter_kernel<<<N_EDGES / 256, 256, 0, stream>>>(ei, (const u16*)score_b,
        (u32*)nd_b, (u32*)ns_b, (u32*)ipay_b, (u32*)opay_b);
    gather_kernel<<<N_NODES / 2, 256, 0, stream>>>((const u32*)xb_b,
        (const u32*)ipay_b, (const u32*)opay_b,
        (const u32*)cnt_b, (const u32*)sd_b, (const u32*)cnt_b + N_NODES, (const u32*)ss_b,
        Y, (float*)ssin_b, (float*)ssout_b);
    finale_mfma_kernel<<<N_NODES / 16, 256, 0, stream>>>((const u32*)Y, x,
        (const u16*)pkM_b, (const u16*)pkG_b, b_s2d, b_d2s,
        (const float*)ssin_b, (const float*)ssout_b,
        (const u32*)cnt_b, (const u32*)cnt_b + N_NODES,
        b_g1, w_g2, b_g2, out);
}